// Round 11
// baseline (213.047 us; speedup 1.0000x reference)
//
#include <hip/hip_runtime.h>

#define T_SEQ 2048
#define BATCH 2
#define HEADS 8
#define DHEAD 64
#define EMB   512

typedef __attribute__((ext_vector_type(8))) short short8;
typedef __attribute__((ext_vector_type(4))) float floatx4;
typedef __attribute__((ext_vector_type(8))) unsigned short ushort8;
typedef __attribute__((ext_vector_type(4))) unsigned short ushort4v;

// RNE convert (cold paths)
__device__ __forceinline__ unsigned short f2b(float f) {
    union { float f; unsigned u; } v; v.f = f;
    unsigned r = v.u + 0x7fffu + ((v.u >> 16) & 1u);
    return (unsigned short)(r >> 16);
}
// 1-op truncating convert (hot paths)
__device__ __forceinline__ unsigned short f2bt(float f) {
    union { float f; unsigned u; } v; v.f = f;
    return (unsigned short)(v.u >> 16);
}
__device__ __forceinline__ float b2f(unsigned short s) {
    union { unsigned u; float f; } v; v.u = ((unsigned)s) << 16; return v.f;
}
__device__ __forceinline__ short8 ld_frag(const unsigned short* p) {
    ushort4v lo = *(const ushort4v*)p;
    ushort4v hi = *(const ushort4v*)(p + 4);
    short8 r;
    r[0] = lo[0]; r[1] = lo[1]; r[2] = lo[2]; r[3] = lo[3];
    r[4] = hi[0]; r[5] = hi[1]; r[6] = hi[2]; r[7] = hi[3];
    return r;
}
// 16B global fragment load (global_load_dwordx4)
__device__ __forceinline__ short8 ldg_frag(const unsigned short* p) {
    union { ushort8 u; short8 s; } c;
    c.u = *(const ushort8*)p;
    return c.s;
}
__device__ __forceinline__ void st8(unsigned short* p, ushort8 v) {
    ushort4v lo = { v[0], v[1], v[2], v[3] };
    ushort4v hi = { v[4], v[5], v[6], v[7] };
    *(ushort4v*)p = lo;
    *(ushort4v*)(p + 4) = hi;
}
// async global->LDS 16B: per-lane global src, wave-uniform LDS base + lane*16
__device__ __forceinline__ void gl16(const unsigned short* g, unsigned short* l) {
    __builtin_amdgcn_global_load_lds(
        (const __attribute__((address_space(1))) unsigned int*)g,
        (__attribute__((address_space(3))) unsigned int*)l, 16, 0, 0);
}
#define MFMA16(a, b, c) __builtin_amdgcn_mfma_f32_16x16x32_bf16(a, b, c, 0, 0, 0)

// ---------------------------------------------------------------------------
// One-shot fp32 -> bf16 conversion of all 5 tensors. (R7: folding this into
// the GEMMs multiplies global traffic -- keep standalone.)
// ---------------------------------------------------------------------------
__global__ __launch_bounds__(256)
void cvt_all(const float* __restrict__ s0, const float* __restrict__ s1,
             const float* __restrict__ s2, const float* __restrict__ s3,
             const float* __restrict__ s4,
             unsigned short* __restrict__ d0, unsigned short* __restrict__ d1,
             unsigned short* __restrict__ d2, unsigned short* __restrict__ d3,
             unsigned short* __restrict__ d4)
{
    const int i = blockIdx.x * 256 + threadIdx.x;
    const float* s; unsigned short* d; int off;
    if      (i <  524288) { s = s0; d = d0; off = i; }
    else if (i <  786432) { s = s1; d = d1; off = i -  524288; }
    else if (i <  983040) { s = s2; d = d2; off = i -  786432; }
    else if (i < 1048576) { s = s3; d = d3; off = i -  983040; }
    else if (i < 1114112) { s = s4; d = d4; off = i - 1048576; }
    else return;
    const float4 v = ((const float4*)s)[off];
    ushort4v o = { f2b(v.x), f2b(v.y), f2b(v.z), f2b(v.w) };
    ((ushort4v*)d)[off] = o;
}

// ---------------------------------------------------------------------------
// Fused QKV + pos projection GEMM (R10 proven).
// grid 64x12 (QKV) + 32x4 (pos) = 896 blocks; gload_lds dbuf staging;
// linear LDS + both-sides XOR swizzle. 3 blocks/CU, 12 waves/CU.
// LDS: buf0 A@0(4096) B@4096(8192) | buf1 @12288 = 24,576 ush = 49,152 B.
// ---------------------------------------------------------------------------
__global__ __launch_bounds__(256)
void gemm_qkv_pos(const unsigned short* __restrict__ inb, const unsigned short* __restrict__ w_inb,
                  const float* __restrict__ b_in,
                  const unsigned short* __restrict__ posb, const unsigned short* __restrict__ w_posb,
                  const float* __restrict__ b_pos,
                  unsigned short* __restrict__ q_s, unsigned short* __restrict__ k_s,
                  unsigned short* __restrict__ vT, unsigned short* __restrict__ r_b)
{
    __shared__ unsigned short shmem[24576];
    unsigned short* tb = shmem;        // 128x67 transpose buf alias (post-loop)

    const int id = blockIdx.x;
    const bool isPos = (id >= 768);
    const int bx = isPos ? ((id - 768) & 3) : (id % 12);
    const int by = isPos ? ((id - 768) >> 2) : (id / 12);
    const unsigned short* A = isPos ? posb : inb;
    const unsigned short* B = isPos ? w_posb : w_inb;
    const float* bias = isPos ? b_pos : b_in;

    const int bm  = by * 64;
    const int bn  = bx * 128;
    const int tid = threadIdx.x;
    const int lane = tid & 63, w = tid >> 6;
    const int m16 = lane & 15, quad = lane >> 4;
    const int wm = (w & 1) * 32, wn = (w >> 1) * 64;
    const int lrow = lane >> 3;        // 0..7 within 8-row chunk
    const int lcol8 = lane & 7;        // 16B col block

    floatx4 acc[2][4];
    #pragma unroll
    for (int i = 0; i < 2; ++i)
        #pragma unroll
        for (int j = 0; j < 4; ++j) acc[i][j] = (floatx4){0.f, 0.f, 0.f, 0.f};

    auto stage = [&](int q, int k0) {
        unsigned short* Ad = shmem + q * 12288;
        unsigned short* Bd = Ad + 4096;
        #pragma unroll
        for (int i = 0; i < 2; ++i) {              // A: 16 rows/wave
            const int rb  = w * 16 + i * 8;
            const int row = rb + lrow;
            const int sc  = ((lcol8 ^ (row & 7)) * 8);
            gl16(A + (size_t)(bm + row) * 512 + k0 + sc, Ad + rb * 64);
        }
        #pragma unroll
        for (int i = 0; i < 4; ++i) {              // B: 32 rows/wave
            const int rb  = w * 32 + i * 8;
            const int row = rb + lrow;
            const int sc  = ((lcol8 ^ (row & 7)) * 8);
            gl16(B + (size_t)(bn + row) * 512 + k0 + sc, Bd + rb * 64);
        }
    };
    auto frag = [&](const unsigned short* Ts, int row, int ks) {
        const int u = (ks * 4 + quad) ^ (row & 7);
        return ld_frag(&Ts[row * 64 + u * 8]);
    };

    stage(0, 0);
    __syncthreads();

    for (int kt = 0; kt < 8; ++kt) {
        const int p = kt & 1;
        unsigned short* As = shmem + p * 12288;
        unsigned short* Bs = As + 4096;
        if (kt + 1 < 8) stage(1 - p, (kt + 1) * 64);
        #pragma unroll
        for (int ks = 0; ks < 2; ++ks) {
            short8 af[2], bf[4];
            #pragma unroll
            for (int f = 0; f < 2; ++f)
                af[f] = frag(As, wm + f * 16 + m16, ks);
            #pragma unroll
            for (int f = 0; f < 4; ++f)
                bf[f] = frag(Bs, wn + f * 16 + m16, ks);
            #pragma unroll
            for (int fm = 0; fm < 2; ++fm)
                #pragma unroll
                for (int fn = 0; fn < 4; ++fn)
                    acc[fm][fn] = MFMA16(af[fm], bf[fn], acc[fm][fn]);
        }
        __syncthreads();
    }

    if (isPos) {
        #pragma unroll
        for (int fn = 0; fn < 4; ++fn) {
            const int n = bn + wn + fn * 16 + m16;
            const float bv = bias[n];
            #pragma unroll
            for (int fm = 0; fm < 2; ++fm)
                #pragma unroll
                for (int rgi = 0; rgi < 4; ++rgi) {
                    const int m = bm + wm + fm * 16 + quad * 4 + rgi;
                    r_b[(size_t)m * EMB + n] = f2b(acc[fm][fn][rgi] + bv);
                }
        }
    } else if (bn < 1024) {
        #pragma unroll
        for (int fn = 0; fn < 4; ++fn) {
            const int n = bn + wn + fn * 16 + m16;
            const float bv = bias[n];
            const int reg = n >> 9, c = n & 511, h = c >> 6, dd = c & 63;
            unsigned short* dst = reg == 0 ? q_s : k_s;
            #pragma unroll
            for (int fm = 0; fm < 2; ++fm)
                #pragma unroll
                for (int rgi = 0; rgi < 4; ++rgi) {
                    const int m = bm + wm + fm * 16 + quad * 4 + rgi;
                    const int t = m >> 1, b = m & 1;
                    dst[((size_t)(b * HEADS + h) * T_SEQ + t) * DHEAD + dd] = f2b(acc[fm][fn][rgi] + bv);
                }
        }
    } else {
        // vT transpose: tb 128x67 (aliases buffers -- dead after final barrier)
        #pragma unroll
        for (int fn = 0; fn < 4; ++fn) {
            const int nl = wn + fn * 16 + m16;
            const float bv = bias[bn + nl];
            #pragma unroll
            for (int fm = 0; fm < 2; ++fm)
                #pragma unroll
                for (int rgi = 0; rgi < 4; ++rgi) {
                    const int ml = wm + fm * 16 + quad * 4 + rgi;
                    tb[nl * 67 + ml] = f2b(acc[fm][fn][rgi] + bv);
                }
        }
        __syncthreads();
        const int t0g = bm >> 1;
        for (int s2 = tid; s2 < 1024; s2 += 256) {
            const int nl = s2 >> 3;            // [0,128)
            const int bsel = (s2 >> 2) & 1;
            const int j = s2 & 3;              // [0,4): 8 t-values each
            ushort8 o;
            #pragma unroll
            for (int k = 0; k < 8; ++k)
                o[k] = tb[nl * 67 + ((j * 8 + k) * 2 + bsel)];
            const int c = bn + nl - 1024, h = c >> 6, dd = c & 63;
            *(ushort8*)(vT + ((size_t)(bsel * HEADS + h) * DHEAD + dd) * T_SEQ + t0g + j * 8) = o;
        }
    }
}

// ---------------------------------------------------------------------------
// Output GEMM: ctx bf16 [4096,512] x w_out bf16 -> fp32 out. (R10 proven)
// 64x64 tiles, grid (8,64) = 512 blocks, gload_lds dbuf. LDS 32,768 B.
// ---------------------------------------------------------------------------
__global__ __launch_bounds__(256)
void gemm_out(const unsigned short* __restrict__ A, const unsigned short* __restrict__ B,
              const float* __restrict__ bias, float* __restrict__ out)
{
    __shared__ unsigned short shmem[16384];
    const int bm  = blockIdx.y * 64;
    const int bn  = blockIdx.x * 64;
    const int tid = threadIdx.x;
    const int lane = tid & 63, w = tid >> 6;
    const int m16 = lane & 15, quad = lane >> 4;
    const int wm = (w & 1) * 32, wn = (w >> 1) * 32;
    const int lrow = lane >> 3;
    const int lcol8 = lane & 7;

    floatx4 acc[2][2];
    #pragma unroll
    for (int i = 0; i < 2; ++i)
        #pragma unroll
        for (int j = 0; j < 2; ++j) acc[i][j] = (floatx4){0.f, 0.f, 0.f, 0.f};

    auto stage = [&](int q, int k0) {
        unsigned short* Ad = shmem + q * 8192;
        unsigned short* Bd = Ad + 4096;
        #pragma unroll
        for (int i = 0; i < 2; ++i) {
            const int rb  = w * 16 + i * 8;
            const int row = rb + lrow;
            const int sc  = ((lcol8 ^ (row & 7)) * 8);
            gl16(A + (size_t)(bm + row) * 512 + k0 + sc, Ad + rb * 64);
            gl16(B + (size_t)(bn + row) * 512 + k0 + sc, Bd + rb * 64);
        }
    };
    auto frag = [&](const unsigned short* Ts, int row, int ks) {
        const int u = (ks * 4 + quad) ^ (row & 7);
        return ld_frag(&Ts[row * 64 + u * 8]);
    };

    stage(0, 0);
    __syncthreads();

    for (int kt = 0; kt < 8; ++kt) {
        const int p = kt & 1;
        unsigned short* As = shmem + p * 8192;
        unsigned short* Bs = As + 4096;
        if (kt + 1 < 8) stage(1 - p, (kt + 1) * 64);
        #pragma unroll
        for (int ks = 0; ks < 2; ++ks) {
            short8 af[2], bf[2];
            #pragma unroll
            for (int f = 0; f < 2; ++f) {
                af[f] = frag(As, wm + f * 16 + m16, ks);
                bf[f] = frag(Bs, wn + f * 16 + m16, ks);
            }
            #pragma unroll
            for (int fm = 0; fm < 2; ++fm)
                #pragma unroll
                for (int fn = 0; fn < 2; ++fn)
                    acc[fm][fn] = MFMA16(af[fm], bf[fn], acc[fm][fn]);
        }
        __syncthreads();
    }

    #pragma unroll
    for (int fn = 0; fn < 2; ++fn) {
        const int n = bn + wn + fn * 16 + m16;
        const float bv = bias[n];
        #pragma unroll
        for (int fm = 0; fm < 2; ++fm)
            #pragma unroll
            for (int rgi = 0; rgi < 4; ++rgi) {
                const int m = bm + wm + fm * 16 + quad * 4 + rgi;
                out[(size_t)m * EMB + n] = acc[fm][fn][rgi] + bv;
            }
    }
}

// ---------------------------------------------------------------------------
// Fused MFMA attention — R11: direct-register R fragments.
//   bd[t][s] = QR[t][T-1-t+s] (s<=t) | 0 (s==t+1) | QR[t+1][s-t-2] (s>=t+2)
// DS census (R10 version): 671 cyc/wave/tile -> LDS pipe ~79% busy = the
// real roofline. R round-trip (8 b128 reads + 2 b128 staging writes + rp
// buffers) removed: R fragments load direct global->regs (addressing+clamps
// validated by R4/R5), issued at tile top, consumed after AC (~350cyc cover
// > L2 ~200). K/V stay LDS-staged (R5 showed all-direct fails). Census
// 671 -> ~550 (-18% on the saturated pipe). Diagonal's 3 extra barriers
// gone (register R, no buffer reuse). Ring/pbuf indexing byte-identical.
// LDS (u16 off): k@0 (2x4352) v@8704 (2x4352) pbuf@17408 (4352)
// ring@21760 (64x133=8512) = 30,272 ush = 60,544 B -> 2 blocks/CU.
// Prologue overlay: qrw_s@0 (64x68), qrr_s@4352 (65x68) - dead before
// store_bufs(0) overwrites (guarded by first barrier).
// ---------------------------------------------------------------------------
__global__ __launch_bounds__(256)
void attn_mfma(const unsigned short* __restrict__ qg_, const unsigned short* __restrict__ kg_,
               const unsigned short* __restrict__ vtg_, const unsigned short* __restrict__ rg_,
               const float* __restrict__ rwb, const float* __restrict__ rrb,
               unsigned short* __restrict__ ctx)
{
    const int T   = T_SEQ;
    const int tb  = blockIdx.x;
    const int t0  = tb * 64;
    const int bh  = blockIdx.y;
    const int h   = bh & 7;
    const int b   = bh >> 3;
    const int tid = threadIdx.x;
    const int lane = tid & 63;
    const int w    = tid >> 6;
    const int m16  = lane & 15;
    const int quad = lane >> 4;
    const int ibase = 16 * w + quad * 4;

    __shared__ unsigned short lds[30272];
    unsigned short* pbuf  = lds + 17408;
    unsigned short* ring  = lds + 21760;
    unsigned short* qrw_s = lds;
    unsigned short* qrr_s = lds + 4352;

    const unsigned short* qg  = qg_  + ((size_t)bh * T + t0) * DHEAD;
    const unsigned short* kg  = kg_  + (size_t)bh * T * DHEAD;
    const unsigned short* vtg = vtg_ + (size_t)bh * DHEAD * T;
    const unsigned short* rg  = rg_  + h * DHEAD;

    const float QSCALE = 0.125f * 1.44269504089f;
    for (int idx = tid; idx < 65 * 16; idx += 256) {
        const int row = idx >> 4, c = (idx & 15) << 2;
        ushort4v qv = {0, 0, 0, 0};
        if (t0 + row < T) qv = *(const ushort4v*)(qg + row * DHEAD + c);
        const float4 rr = *(const float4*)(rrb + h * DHEAD + c);
        qrr_s[row * 68 + c + 0] = f2b((b2f(qv[0]) + rr.x) * QSCALE);
        qrr_s[row * 68 + c + 1] = f2b((b2f(qv[1]) + rr.y) * QSCALE);
        qrr_s[row * 68 + c + 2] = f2b((b2f(qv[2]) + rr.z) * QSCALE);
        qrr_s[row * 68 + c + 3] = f2b((b2f(qv[3]) + rr.w) * QSCALE);
        if (row < 64) {
            const float4 rw = *(const float4*)(rwb + h * DHEAD + c);
            qrw_s[row * 68 + c + 0] = f2b((b2f(qv[0]) + rw.x) * QSCALE);
            qrw_s[row * 68 + c + 1] = f2b((b2f(qv[1]) + rw.y) * QSCALE);
            qrw_s[row * 68 + c + 2] = f2b((b2f(qv[2]) + rw.z) * QSCALE);
            qrw_s[row * 68 + c + 3] = f2b((b2f(qv[3]) + rw.w) * QSCALE);
        }
    }
    __syncthreads();

    short8 a_ac[2], a_qrl[2], a_qru[2];
    {
        const unsigned short* p0 = &qrw_s[(16 * w + m16) * 68 + quad * 8];
        a_ac[0]  = ld_frag(p0);  a_ac[1]  = ld_frag(p0 + 32);
        const unsigned short* p1 = &qrr_s[(16 * w + m16) * 68 + quad * 8];
        a_qrl[0] = ld_frag(p1);  a_qrl[1] = ld_frag(p1 + 32);
        const unsigned short* p2 = &qrr_s[(16 * w + 1 + m16) * 68 + quad * 8];
        a_qru[0] = ld_frag(p2);  a_qru[1] = ld_frag(p2 + 32);
    }

    const int srow0 = tid >> 3,          scol0 = (tid & 7) * 8;
    const int srow1 = (tid + 256) >> 3,  scol1 = (tid & 7) * 8;

    ushort8 kr[2], vr[2];
    auto prefetch = [&](int s0n) {
        kr[0]  = *(const ushort8*)(kg + (size_t)(s0n + srow0) * DHEAD + scol0);
        kr[1]  = *(const ushort8*)(kg + (size_t)(s0n + srow1) * DHEAD + scol1);
        vr[0]  = *(const ushort8*)(vtg + (size_t)srow0 * T + s0n + scol0);
        vr[1]  = *(const ushort8*)(vtg + (size_t)srow1 * T + s0n + scol1);
    };
    auto store_bufs = [&](int q) {
        unsigned short* kb = lds + q * 4352;
        unsigned short* vb = lds + 8704 + q * 4352;
        st8(&kb[srow0 * 68 + scol0], kr[0]);
        st8(&kb[srow1 * 68 + scol1], kr[1]);
        st8(&vb[srow0 * 68 + scol0], vr[0]);
        st8(&vb[srow1 * 68 + scol1], vr[1]);
    };
    // R fragments direct global->regs (rows clamp(jbase + 16cc + m16)),
    // exact addressing validated in R4/R5 correctness runs.
    auto ldR = [&](int jbase, short8 (&rr)[4][2]) {
        #pragma unroll
        for (int cc = 0; cc < 4; ++cc) {
            int j = jbase + 16 * cc + m16; j = j < 0 ? 0 : (j > T - 1 ? T - 1 : j);
            const unsigned short* rrow = rg + (size_t)j * EMB + quad * 8;
            rr[cc][0] = ldg_frag(rrow);
            rr[cc][1] = ldg_frag(rrow + 32);
        }
    };
    auto qr_from = [&](short8 (&rr)[4][2], const short8* aq, int slotbase) {
        #pragma unroll
        for (int cc = 0; cc < 4; ++cc) {
            floatx4 q4 = (floatx4){0.f, 0.f, 0.f, 0.f};
            q4 = MFMA16(aq[0], rr[cc][0], q4);
            q4 = MFMA16(aq[1], rr[cc][1], q4);
            #pragma unroll
            for (int rgi = 0; rgi < 4; ++rgi)
                ring[(ibase + rgi) * 133 + slotbase + 16 * cc + m16] = f2bt(q4[rgi]);
        }
    };

    floatx4 O[4];
    float lrun[4];
    #pragma unroll
    for (int ct = 0; ct < 4; ++ct) O[ct] = (floatx4){0.f, 0.f, 0.f, 0.f};
    #pragma unroll
    for (int rgi = 0; rgi < 4; ++rgi) lrun[rgi] = 0.f;

    short8 rf[4][2];
    {
        ldR(T - t0 - 64, rf);              // prologue ring half, direct
        prefetch(0);
        __syncthreads();                   // a-frag extraction done block-wide
        qr_from(rf, a_qrl, 0);
        store_bufs(0);                     // overwrites overlay region (safe)
        __syncthreads();
    }

    for (int na = 0; na < T / 64; ++na) {
        const int s0 = na * 64;
        const int p = na & 1;
        unsigned short* kb = lds + p * 4352;
        unsigned short* vb = lds + 8704 + p * 4352;
        const bool lower = (s0 <= t0);
        const int nph    = lower ? (s0 >> 6) : ((s0 - t0) >> 6);
        const int rbase  = (nph & 1) * 64;
        const int wbase  = 64 - rbase;
        const bool diag  = (s0 == t0);
        const bool hasNext = (na + 1 < T / 64);

        // issue R loads first: consumed at qr_from after AC (~350cyc cover)
        if (!diag) ldR(lower ? (s0 + T - t0) : (s0 - t0 - 1), rf);

        floatx4 acf[4];
        __builtin_amdgcn_s_setprio(1);
        #pragma unroll
        for (int ct = 0; ct < 4; ++ct) {
            acf[ct] = (floatx4){0.f, 0.f, 0.f, 0.f};
            #pragma unroll
            for (int ks = 0; ks < 2; ++ks) {
                short8 bfr = ld_frag(&kb[(16 * ct + m16) * 68 + ks * 32 + quad * 8]);
                acf[ct] = MFMA16(a_ac[ks], bfr, acf[ct]);
            }
        }
        __builtin_amdgcn_s_setprio(0);
        if (hasNext) prefetch(s0 + 64);

        if (!diag) {
            qr_from(rf, lower ? a_qrl : a_qru, wbase);
            #pragma unroll
            for (int ct = 0; ct < 4; ++ct) {
                #pragma unroll
                for (int rgi = 0; rgi < 4; ++rgi) {
                    const int i = ibase + rgi;
                    const int slot = ((63 - i + 16 * ct + m16) + rbase) & 127;
                    acf[ct][rgi] += b2f(ring[i * 133 + slot]);
                }
            }
            if (s0 == t0 + 64 && lane == 48 && w == 3)
                acf[0][3] -= b2f(ring[63 * 133 + (rbase & 127)]);
        } else {
            #pragma unroll
            for (int ct = 0; ct < 4; ++ct) {
                #pragma unroll
                for (int rgi = 0; rgi < 4; ++rgi) {
                    const int i = ibase + rgi, u = 16 * ct + m16;
                    if (u <= i) acf[ct][rgi] += b2f(ring[i * 133 + (((63 - i + u) + rbase) & 127)]);
                }
            }
            // diagonal upper half: direct R regs, no barriers needed
            ldR(-1, rf);
            qr_from(rf, a_qru, 64);
            #pragma unroll
            for (int ct = 0; ct < 4; ++ct) {
                #pragma unroll
                for (int rgi = 0; rgi < 4; ++rgi) {
                    const int i = ibase + rgi, u = 16 * ct + m16;
                    if (u >= i + 2) acf[ct][rgi] += b2f(ring[i * 133 + 63 - i + u]);
                }
            }
        }

        #pragma unroll
        for (int rgi = 0; rgi < 4; ++rgi) {
            #pragma unroll
            for (int ct = 0; ct < 4; ++ct) {
                const float pv = exp2f(acf[ct][rgi]);
                acf[ct][rgi] = pv;
                lrun[rgi] += pv;
            }
        }
        // P -> dedicated pbuf (same-wave cross-lane exchange, no barrier)
        #pragma unroll
        for (int ct = 0; ct < 4; ++ct)
            #pragma unroll
            for (int rgi = 0; rgi < 4; ++rgi)
                pbuf[(ibase + rgi) * 68 + 16 * ct + m16] = f2bt(acf[ct][rgi]);

        short8 ap[2];
        {
            const unsigned short* pp = &pbuf[(16 * w + m16) * 68 + quad * 8];
            ap[0] = ld_frag(pp); ap[1] = ld_frag(pp + 32);
        }
        __builtin_amdgcn_s_setprio(1);
        #pragma unroll
        for (int ct = 0; ct < 4; ++ct) {
            #pragma unroll
            for (int ks = 0; ks < 2; ++ks) {
                short8 bfr = ld_frag(&vb[(16 * ct + m16) * 68 + ks * 32 + quad * 8]);
                O[ct] = MFMA16(ap[ks], bfr, O[ct]);
            }
        }
        __builtin_amdgcn_s_setprio(0);
        if (hasNext) store_bufs(1 - p);
        __syncthreads();                       // single tile-boundary barrier
    }

    #pragma unroll
    for (int rgi = 0; rgi < 4; ++rgi) {
        float l = lrun[rgi];
        #pragma unroll
        for (int off = 1; off < 16; off <<= 1)
            l += __shfl_xor(l, off);
        const float inv = 1.f / l;
        const int t = t0 + ibase + rgi;
        #pragma unroll
        for (int ct = 0; ct < 4; ++ct)
            ctx[((size_t)t * BATCH + b) * EMB + h * DHEAD + 16 * ct + m16] = f2bt(O[ct][rgi] * inv);
    }
}

// ---------------------------------------------------------------------------
// Workspace (ushort offsets), 15,990,784 ush = 31.98 MB:
//   0 inb | 2097152 posb | 3145728 w_inb | 3932160 w_posb | 4194304 free |
//   6291456 w_outb | 6553600 q_s | 8650752 k_s | 10747904 vT | 12845056 r_b |
//   13893632 ctx_b
// ---------------------------------------------------------------------------
extern "C" void kernel_launch(void* const* d_in, const int* in_sizes, int n_in,
                              void* d_out, int out_size, void* d_ws, size_t ws_size,
                              hipStream_t stream)
{
    const float* input = (const float*)d_in[0];
    const float* pos   = (const float*)d_in[1];
    const float* w_in  = (const float*)d_in[2];
    const float* w_out = (const float*)d_in[3];
    const float* w_pos = (const float*)d_in[4];
    const float* b_in  = (const float*)d_in[5];
    const float* b_out = (const float*)d_in[6];
    const float* b_pos = (const float*)d_in[7];
    const float* rwb   = (const float*)d_in[8];
    const float* rrb   = (const float*)d_in[9];

    unsigned short* ws     = (unsigned short*)d_ws;
    unsigned short* inb    = ws;
    unsigned short* posb   = ws + 2097152;
    unsigned short* w_inb  = ws + 3145728;
    unsigned short* w_posb = ws + 3932160;
    unsigned short* w_outb = ws + 6291456;
    unsigned short* q_s    = ws + 6553600;
    unsigned short* k_s    = ws + 8650752;
    unsigned short* vT     = ws + 10747904;
    unsigned short* r_b    = ws + 12845056;
    unsigned short* ctx_b  = ws + 13893632;

    cvt_all<<<4352, 256, 0, stream>>>(input, pos, w_in, w_pos, w_out,
                                      inb, posb, w_inb, w_posb, w_outb);
    gemm_qkv_pos<<<896, 256, 0, stream>>>(inb, w_inb, b_in, posb, w_posb, b_pos,
                                          q_s, k_s, vT, r_b);
    attn_mfma<<<dim3(32, 16), 256, 0, stream>>>(q_s, k_s, vT, r_b, rwb, rrb, ctx_b);
    gemm_out<<<dim3(8, 64), 256, 0, stream>>>(ctx_b, w_outb, b_out, (float*)d_out);
}

// Round 12
// 183.658 us; speedup vs baseline: 1.1600x; 1.1600x over previous
//
#include <hip/hip_runtime.h>

#define T_SEQ 2048
#define BATCH 2
#define HEADS 8
#define DHEAD 64
#define EMB   512

typedef __attribute__((ext_vector_type(8))) short short8;
typedef __attribute__((ext_vector_type(4))) float floatx4;
typedef __attribute__((ext_vector_type(8))) unsigned short ushort8;
typedef __attribute__((ext_vector_type(4))) unsigned short ushort4v;

// RNE convert (cold paths)
__device__ __forceinline__ unsigned short f2b(float f) {
    union { float f; unsigned u; } v; v.f = f;
    unsigned r = v.u + 0x7fffu + ((v.u >> 16) & 1u);
    return (unsigned short)(r >> 16);
}
// 1-op truncating convert (hot paths)
__device__ __forceinline__ unsigned short f2bt(float f) {
    union { float f; unsigned u; } v; v.f = f;
    return (unsigned short)(v.u >> 16);
}
__device__ __forceinline__ float b2f(unsigned short s) {
    union { unsigned u; float f; } v; v.u = ((unsigned)s) << 16; return v.f;
}
__device__ __forceinline__ short8 ld_frag(const unsigned short* p) {
    ushort4v lo = *(const ushort4v*)p;
    ushort4v hi = *(const ushort4v*)(p + 4);
    short8 r;
    r[0] = lo[0]; r[1] = lo[1]; r[2] = lo[2]; r[3] = lo[3];
    r[4] = hi[0]; r[5] = hi[1]; r[6] = hi[2]; r[7] = hi[3];
    return r;
}
__device__ __forceinline__ void st8(unsigned short* p, ushort8 v) {
    ushort4v lo = { v[0], v[1], v[2], v[3] };
    ushort4v hi = { v[4], v[5], v[6], v[7] };
    *(ushort4v*)p = lo;
    *(ushort4v*)(p + 4) = hi;
}
// async global->LDS 16B: per-lane global src, wave-uniform LDS base + lane*16
__device__ __forceinline__ void gl16(const unsigned short* g, unsigned short* l) {
    __builtin_amdgcn_global_load_lds(
        (const __attribute__((address_space(1))) unsigned int*)g,
        (__attribute__((address_space(3))) unsigned int*)l, 16, 0, 0);
}
#define MFMA16(a, b, c) __builtin_amdgcn_mfma_f32_16x16x32_bf16(a, b, c, 0, 0, 0)

// ---------------------------------------------------------------------------
// One-shot fp32 -> bf16 conversion of all 5 tensors. (R7: folding this into
// the GEMMs multiplies global traffic -- keep standalone.)
// ---------------------------------------------------------------------------
__global__ __launch_bounds__(256)
void cvt_all(const float* __restrict__ s0, const float* __restrict__ s1,
             const float* __restrict__ s2, const float* __restrict__ s3,
             const float* __restrict__ s4,
             unsigned short* __restrict__ d0, unsigned short* __restrict__ d1,
             unsigned short* __restrict__ d2, unsigned short* __restrict__ d3,
             unsigned short* __restrict__ d4)
{
    const int i = blockIdx.x * 256 + threadIdx.x;
    const float* s; unsigned short* d; int off;
    if      (i <  524288) { s = s0; d = d0; off = i; }
    else if (i <  786432) { s = s1; d = d1; off = i -  524288; }
    else if (i <  983040) { s = s2; d = d2; off = i -  786432; }
    else if (i < 1048576) { s = s3; d = d3; off = i -  983040; }
    else if (i < 1114112) { s = s4; d = d4; off = i - 1048576; }
    else return;
    const float4 v = ((const float4*)s)[off];
    ushort4v o = { f2b(v.x), f2b(v.y), f2b(v.z), f2b(v.w) };
    ((ushort4v*)d)[off] = o;
}

// ---------------------------------------------------------------------------
// Fused QKV + pos projection GEMM (R10 proven).
// grid 64x12 (QKV) + 32x4 (pos) = 896 blocks; gload_lds dbuf staging;
// linear LDS + both-sides XOR swizzle. 3 blocks/CU, 12 waves/CU.
// LDS: buf0 A@0(4096) B@4096(8192) | buf1 @12288 = 24,576 ush = 49,152 B.
// ---------------------------------------------------------------------------
__global__ __launch_bounds__(256)
void gemm_qkv_pos(const unsigned short* __restrict__ inb, const unsigned short* __restrict__ w_inb,
                  const float* __restrict__ b_in,
                  const unsigned short* __restrict__ posb, const unsigned short* __restrict__ w_posb,
                  const float* __restrict__ b_pos,
                  unsigned short* __restrict__ q_s, unsigned short* __restrict__ k_s,
                  unsigned short* __restrict__ vT, unsigned short* __restrict__ r_b)
{
    __shared__ unsigned short shmem[24576];
    unsigned short* tb = shmem;        // 128x67 transpose buf alias (post-loop)

    const int id = blockIdx.x;
    const bool isPos = (id >= 768);
    const int bx = isPos ? ((id - 768) & 3) : (id % 12);
    const int by = isPos ? ((id - 768) >> 2) : (id / 12);
    const unsigned short* A = isPos ? posb : inb;
    const unsigned short* B = isPos ? w_posb : w_inb;
    const float* bias = isPos ? b_pos : b_in;

    const int bm  = by * 64;
    const int bn  = bx * 128;
    const int tid = threadIdx.x;
    const int lane = tid & 63, w = tid >> 6;
    const int m16 = lane & 15, quad = lane >> 4;
    const int wm = (w & 1) * 32, wn = (w >> 1) * 64;
    const int lrow = lane >> 3;        // 0..7 within 8-row chunk
    const int lcol8 = lane & 7;        // 16B col block

    floatx4 acc[2][4];
    #pragma unroll
    for (int i = 0; i < 2; ++i)
        #pragma unroll
        for (int j = 0; j < 4; ++j) acc[i][j] = (floatx4){0.f, 0.f, 0.f, 0.f};

    auto stage = [&](int q, int k0) {
        unsigned short* Ad = shmem + q * 12288;
        unsigned short* Bd = Ad + 4096;
        #pragma unroll
        for (int i = 0; i < 2; ++i) {              // A: 16 rows/wave
            const int rb  = w * 16 + i * 8;
            const int row = rb + lrow;
            const int sc  = ((lcol8 ^ (row & 7)) * 8);
            gl16(A + (size_t)(bm + row) * 512 + k0 + sc, Ad + rb * 64);
        }
        #pragma unroll
        for (int i = 0; i < 4; ++i) {              // B: 32 rows/wave
            const int rb  = w * 32 + i * 8;
            const int row = rb + lrow;
            const int sc  = ((lcol8 ^ (row & 7)) * 8);
            gl16(B + (size_t)(bn + row) * 512 + k0 + sc, Bd + rb * 64);
        }
    };
    auto frag = [&](const unsigned short* Ts, int row, int ks) {
        const int u = (ks * 4 + quad) ^ (row & 7);
        return ld_frag(&Ts[row * 64 + u * 8]);
    };

    stage(0, 0);
    __syncthreads();

    for (int kt = 0; kt < 8; ++kt) {
        const int p = kt & 1;
        unsigned short* As = shmem + p * 12288;
        unsigned short* Bs = As + 4096;
        if (kt + 1 < 8) stage(1 - p, (kt + 1) * 64);
        #pragma unroll
        for (int ks = 0; ks < 2; ++ks) {
            short8 af[2], bf[4];
            #pragma unroll
            for (int f = 0; f < 2; ++f)
                af[f] = frag(As, wm + f * 16 + m16, ks);
            #pragma unroll
            for (int f = 0; f < 4; ++f)
                bf[f] = frag(Bs, wn + f * 16 + m16, ks);
            #pragma unroll
            for (int fm = 0; fm < 2; ++fm)
                #pragma unroll
                for (int fn = 0; fn < 4; ++fn)
                    acc[fm][fn] = MFMA16(af[fm], bf[fn], acc[fm][fn]);
        }
        __syncthreads();
    }

    if (isPos) {
        #pragma unroll
        for (int fn = 0; fn < 4; ++fn) {
            const int n = bn + wn + fn * 16 + m16;
            const float bv = bias[n];
            #pragma unroll
            for (int fm = 0; fm < 2; ++fm)
                #pragma unroll
                for (int rgi = 0; rgi < 4; ++rgi) {
                    const int m = bm + wm + fm * 16 + quad * 4 + rgi;
                    r_b[(size_t)m * EMB + n] = f2b(acc[fm][fn][rgi] + bv);
                }
        }
    } else if (bn < 1024) {
        #pragma unroll
        for (int fn = 0; fn < 4; ++fn) {
            const int n = bn + wn + fn * 16 + m16;
            const float bv = bias[n];
            const int reg = n >> 9, c = n & 511, h = c >> 6, dd = c & 63;
            unsigned short* dst = reg == 0 ? q_s : k_s;
            #pragma unroll
            for (int fm = 0; fm < 2; ++fm)
                #pragma unroll
                for (int rgi = 0; rgi < 4; ++rgi) {
                    const int m = bm + wm + fm * 16 + quad * 4 + rgi;
                    const int t = m >> 1, b = m & 1;
                    dst[((size_t)(b * HEADS + h) * T_SEQ + t) * DHEAD + dd] = f2b(acc[fm][fn][rgi] + bv);
                }
        }
    } else {
        // vT transpose: tb 128x67 (aliases buffers -- dead after final barrier)
        #pragma unroll
        for (int fn = 0; fn < 4; ++fn) {
            const int nl = wn + fn * 16 + m16;
            const float bv = bias[bn + nl];
            #pragma unroll
            for (int fm = 0; fm < 2; ++fm)
                #pragma unroll
                for (int rgi = 0; rgi < 4; ++rgi) {
                    const int ml = wm + fm * 16 + quad * 4 + rgi;
                    tb[nl * 67 + ml] = f2b(acc[fm][fn][rgi] + bv);
                }
        }
        __syncthreads();
        const int t0g = bm >> 1;
        for (int s2 = tid; s2 < 1024; s2 += 256) {
            const int nl = s2 >> 3;            // [0,128)
            const int bsel = (s2 >> 2) & 1;
            const int j = s2 & 3;              // [0,4): 8 t-values each
            ushort8 o;
            #pragma unroll
            for (int k = 0; k < 8; ++k)
                o[k] = tb[nl * 67 + ((j * 8 + k) * 2 + bsel)];
            const int c = bn + nl - 1024, h = c >> 6, dd = c & 63;
            *(ushort8*)(vT + ((size_t)(bsel * HEADS + h) * DHEAD + dd) * T_SEQ + t0g + j * 8) = o;
        }
    }
}

// ---------------------------------------------------------------------------
// Output GEMM: ctx bf16 [4096,512] x w_out bf16 -> fp32 out. (R10 proven)
// 64x64 tiles, grid (8,64) = 512 blocks, gload_lds dbuf. LDS 32,768 B.
// ---------------------------------------------------------------------------
__global__ __launch_bounds__(256)
void gemm_out(const unsigned short* __restrict__ A, const unsigned short* __restrict__ B,
              const float* __restrict__ bias, float* __restrict__ out)
{
    __shared__ unsigned short shmem[16384];
    const int bm  = blockIdx.y * 64;
    const int bn  = blockIdx.x * 64;
    const int tid = threadIdx.x;
    const int lane = tid & 63, w = tid >> 6;
    const int m16 = lane & 15, quad = lane >> 4;
    const int wm = (w & 1) * 32, wn = (w >> 1) * 32;
    const int lrow = lane >> 3;
    const int lcol8 = lane & 7;

    floatx4 acc[2][2];
    #pragma unroll
    for (int i = 0; i < 2; ++i)
        #pragma unroll
        for (int j = 0; j < 2; ++j) acc[i][j] = (floatx4){0.f, 0.f, 0.f, 0.f};

    auto stage = [&](int q, int k0) {
        unsigned short* Ad = shmem + q * 8192;
        unsigned short* Bd = Ad + 4096;
        #pragma unroll
        for (int i = 0; i < 2; ++i) {
            const int rb  = w * 16 + i * 8;
            const int row = rb + lrow;
            const int sc  = ((lcol8 ^ (row & 7)) * 8);
            gl16(A + (size_t)(bm + row) * 512 + k0 + sc, Ad + rb * 64);
            gl16(B + (size_t)(bn + row) * 512 + k0 + sc, Bd + rb * 64);
        }
    };
    auto frag = [&](const unsigned short* Ts, int row, int ks) {
        const int u = (ks * 4 + quad) ^ (row & 7);
        return ld_frag(&Ts[row * 64 + u * 8]);
    };

    stage(0, 0);
    __syncthreads();

    for (int kt = 0; kt < 8; ++kt) {
        const int p = kt & 1;
        unsigned short* As = shmem + p * 8192;
        unsigned short* Bs = As + 4096;
        if (kt + 1 < 8) stage(1 - p, (kt + 1) * 64);
        #pragma unroll
        for (int ks = 0; ks < 2; ++ks) {
            short8 af[2], bf[2];
            #pragma unroll
            for (int f = 0; f < 2; ++f) {
                af[f] = frag(As, wm + f * 16 + m16, ks);
                bf[f] = frag(Bs, wn + f * 16 + m16, ks);
            }
            #pragma unroll
            for (int fm = 0; fm < 2; ++fm)
                #pragma unroll
                for (int fn = 0; fn < 2; ++fn)
                    acc[fm][fn] = MFMA16(af[fm], bf[fn], acc[fm][fn]);
        }
        __syncthreads();
    }

    #pragma unroll
    for (int fn = 0; fn < 2; ++fn) {
        const int n = bn + wn + fn * 16 + m16;
        const float bv = bias[n];
        #pragma unroll
        for (int fm = 0; fm < 2; ++fm)
            #pragma unroll
            for (int rgi = 0; rgi < 4; ++rgi) {
                const int m = bm + wm + fm * 16 + quad * 4 + rgi;
                out[(size_t)m * EMB + n] = acc[fm][fn][rgi] + bv;
            }
    }
}

// ---------------------------------------------------------------------------
// Fused MFMA attention — R1/R10 proven version (~90.5 us), barrier-reduced.
//   bd[t][s] = QR[t][T-1-t+s] (s<=t) | 0 (s==t+1) | QR[t+1][s-t-2] (s>=t+2)
// CONVERGED LOCAL OPTIMUM: 8 structural attacks (barrier cut, LDS-occupancy,
// s-split+atomics, all-direct-global, reg-prefetch, direct-R) all landed at
// or below this. Mechanism: at 2 waves/SIMD, LDS-staged operands with the
// tile-end barrier drain beat any same-tile global->reg load (vmcnt waits
// expose ~200-900cyc un-pipelined; ds_read_b128 latency overlaps).
// Wave-privacy facts (rows ibase+rgi = 16w+quad*4+rgi): ring rows and pbuf
// rows are wave-private -> no barrier between qr_half/ring adds, nor around
// the P round-trip. ONE barrier per s-tile at tile end. Diagonal Bd1-Bd3.
// LDS (u16): k@0 (2x4352) v@8704 (2x4352) rp@17408 (2x4352) pbuf@26112
// (4352) ring@30464 (64x133 = 8512). 77,952 B -> 2 blocks/CU.
// ---------------------------------------------------------------------------
__global__ __launch_bounds__(256)
void attn_mfma(const unsigned short* __restrict__ qg_, const unsigned short* __restrict__ kg_,
               const unsigned short* __restrict__ vtg_, const unsigned short* __restrict__ rg_,
               const float* __restrict__ rwb, const float* __restrict__ rrb,
               unsigned short* __restrict__ ctx)
{
    const int T   = T_SEQ;
    const int tb  = blockIdx.x;
    const int t0  = tb * 64;
    const int bh  = blockIdx.y;
    const int h   = bh & 7;
    const int b   = bh >> 3;
    const int tid = threadIdx.x;
    const int lane = tid & 63;
    const int w    = tid >> 6;
    const int m16  = lane & 15;
    const int quad = lane >> 4;
    const int ibase = 16 * w + quad * 4;

    __shared__ unsigned short lds[38976];
    unsigned short* pbuf  = lds + 26112;
    unsigned short* ring  = lds + 30464;
    unsigned short* qrw_s = lds;
    unsigned short* qrr_s = lds + 8704;

    const unsigned short* qg  = qg_  + ((size_t)bh * T + t0) * DHEAD;
    const unsigned short* kg  = kg_  + (size_t)bh * T * DHEAD;
    const unsigned short* vtg = vtg_ + (size_t)bh * DHEAD * T;
    const unsigned short* rg  = rg_  + h * DHEAD;

    const float QSCALE = 0.125f * 1.44269504089f;
    for (int idx = tid; idx < 65 * 16; idx += 256) {
        const int row = idx >> 4, c = (idx & 15) << 2;
        ushort4v qv = {0, 0, 0, 0};
        if (t0 + row < T) qv = *(const ushort4v*)(qg + row * DHEAD + c);
        const float4 rr = *(const float4*)(rrb + h * DHEAD + c);
        qrr_s[row * 68 + c + 0] = f2b((b2f(qv[0]) + rr.x) * QSCALE);
        qrr_s[row * 68 + c + 1] = f2b((b2f(qv[1]) + rr.y) * QSCALE);
        qrr_s[row * 68 + c + 2] = f2b((b2f(qv[2]) + rr.z) * QSCALE);
        qrr_s[row * 68 + c + 3] = f2b((b2f(qv[3]) + rr.w) * QSCALE);
        if (row < 64) {
            const float4 rw = *(const float4*)(rwb + h * DHEAD + c);
            qrw_s[row * 68 + c + 0] = f2b((b2f(qv[0]) + rw.x) * QSCALE);
            qrw_s[row * 68 + c + 1] = f2b((b2f(qv[1]) + rw.y) * QSCALE);
            qrw_s[row * 68 + c + 2] = f2b((b2f(qv[2]) + rw.z) * QSCALE);
            qrw_s[row * 68 + c + 3] = f2b((b2f(qv[3]) + rw.w) * QSCALE);
        }
    }
    __syncthreads();

    short8 a_ac[2], a_qrl[2], a_qru[2];
    {
        const unsigned short* p0 = &qrw_s[(16 * w + m16) * 68 + quad * 8];
        a_ac[0]  = ld_frag(p0);  a_ac[1]  = ld_frag(p0 + 32);
        const unsigned short* p1 = &qrr_s[(16 * w + m16) * 68 + quad * 8];
        a_qrl[0] = ld_frag(p1);  a_qrl[1] = ld_frag(p1 + 32);
        const unsigned short* p2 = &qrr_s[(16 * w + 1 + m16) * 68 + quad * 8];
        a_qru[0] = ld_frag(p2);  a_qru[1] = ld_frag(p2 + 32);
    }

    const int srow0 = tid >> 3,          scol0 = (tid & 7) * 8;
    const int srow1 = (tid + 256) >> 3,  scol1 = (tid & 7) * 8;

    ushort8 kr[2], vr[2], rr8[2];
    auto prefetch = [&](int s0n) {
        const bool ln = (s0n <= t0);
        const int jb = (ln ? (s0n + T - t0 - 64) : (s0n - t0 - 65)) + 64;
        int j0 = jb + srow0; j0 = j0 < 0 ? 0 : (j0 > T - 1 ? T - 1 : j0);
        int j1 = jb + srow1; j1 = j1 < 0 ? 0 : (j1 > T - 1 ? T - 1 : j1);
        kr[0]  = *(const ushort8*)(kg + (size_t)(s0n + srow0) * DHEAD + scol0);
        kr[1]  = *(const ushort8*)(kg + (size_t)(s0n + srow1) * DHEAD + scol1);
        vr[0]  = *(const ushort8*)(vtg + (size_t)srow0 * T + s0n + scol0);
        vr[1]  = *(const ushort8*)(vtg + (size_t)srow1 * T + s0n + scol1);
        rr8[0] = *(const ushort8*)(rg + (size_t)j0 * EMB + scol0);
        rr8[1] = *(const ushort8*)(rg + (size_t)j1 * EMB + scol1);
    };
    auto store_bufs = [&](int q) {
        unsigned short* kb = lds + q * 4352;
        unsigned short* vb = lds + 8704 + q * 4352;
        unsigned short* rb = lds + 17408 + q * 4352;
        st8(&kb[srow0 * 68 + scol0], kr[0]);
        st8(&kb[srow1 * 68 + scol1], kr[1]);
        st8(&vb[srow0 * 68 + scol0], vr[0]);
        st8(&vb[srow1 * 68 + scol1], vr[1]);
        st8(&rb[srow0 * 68 + scol0], rr8[0]);
        st8(&rb[srow1 * 68 + scol1], rr8[1]);
    };
    auto stage_to = [&](unsigned short* dstb, int jbase) {
        #pragma unroll
        for (int idx = tid; idx < 512; idx += 256) {
            const int row = idx >> 3, c = (idx & 7) * 8;
            int j = jbase + row; j = j < 0 ? 0 : (j > T - 1 ? T - 1 : j);
            st8(&dstb[row * 68 + c], *(const ushort8*)(rg + (size_t)j * EMB + c));
        }
    };
    auto qr_half = [&](const unsigned short* rsb, const short8* aq, int slotbase) {
        #pragma unroll
        for (int cc = 0; cc < 4; ++cc) {
            floatx4 q4 = (floatx4){0.f, 0.f, 0.f, 0.f};
            #pragma unroll
            for (int ks = 0; ks < 2; ++ks) {
                short8 bfr = ld_frag(&rsb[(16 * cc + m16) * 68 + ks * 32 + quad * 8]);
                q4 = MFMA16(aq[ks], bfr, q4);
            }
            #pragma unroll
            for (int rgi = 0; rgi < 4; ++rgi)
                ring[(ibase + rgi) * 133 + slotbase + 16 * cc + m16] = f2bt(q4[rgi]);
        }
    };

    floatx4 O[4];
    float lrun[4];
    #pragma unroll
    for (int ct = 0; ct < 4; ++ct) O[ct] = (floatx4){0.f, 0.f, 0.f, 0.f};
    #pragma unroll
    for (int rgi = 0; rgi < 4; ++rgi) lrun[rgi] = 0.f;

    {
        stage_to(lds + 17408 + 4352, T - t0 - 64);
        prefetch(0);
        __syncthreads();
        qr_half(lds + 17408 + 4352, a_qrl, 0);
        store_bufs(0);
        __syncthreads();
    }

    for (int na = 0; na < T / 64; ++na) {
        const int s0 = na * 64;
        const int p = na & 1;
        unsigned short* kb = lds + p * 4352;
        unsigned short* vb = lds + 8704 + p * 4352;
        unsigned short* rp = lds + 17408 + p * 4352;
        const bool lower = (s0 <= t0);
        const int nph    = lower ? (s0 >> 6) : ((s0 - t0) >> 6);
        const int rbase  = (nph & 1) * 64;
        const int wbase  = 64 - rbase;
        const bool hasNext = (na + 1 < T / 64);

        floatx4 acf[4];
        __builtin_amdgcn_s_setprio(1);
        #pragma unroll
        for (int ct = 0; ct < 4; ++ct) {
            acf[ct] = (floatx4){0.f, 0.f, 0.f, 0.f};
            #pragma unroll
            for (int ks = 0; ks < 2; ++ks) {
                short8 bfr = ld_frag(&kb[(16 * ct + m16) * 68 + ks * 32 + quad * 8]);
                acf[ct] = MFMA16(a_ac[ks], bfr, acf[ct]);
            }
        }
        __builtin_amdgcn_s_setprio(0);
        if (hasNext) prefetch(s0 + 64);
        qr_half(rp, lower ? a_qrl : a_qru, wbase);
        // no barrier: ring rows are wave-private, DS ops in-order per wave

        if (s0 != t0) {
            #pragma unroll
            for (int ct = 0; ct < 4; ++ct) {
                #pragma unroll
                for (int rgi = 0; rgi < 4; ++rgi) {
                    const int i = ibase + rgi;
                    const int slot = ((63 - i + 16 * ct + m16) + rbase) & 127;
                    acf[ct][rgi] += b2f(ring[i * 133 + slot]);
                }
            }
            if (s0 == t0 + 64 && lane == 48 && w == 3)
                acf[0][3] -= b2f(ring[63 * 133 + (rbase & 127)]);
        } else {
            #pragma unroll
            for (int ct = 0; ct < 4; ++ct) {
                #pragma unroll
                for (int rgi = 0; rgi < 4; ++rgi) {
                    const int i = ibase + rgi, u = 16 * ct + m16;
                    if (u <= i) acf[ct][rgi] += b2f(ring[i * 133 + (((63 - i + u) + rbase) & 127)]);
                }
            }
            unsigned short* rpo = lds + 17408 + (1 - p) * 4352;
            __syncthreads();                   // Bd1
            stage_to(rpo, -1);
            __syncthreads();                   // Bd2
            qr_half(rpo, a_qru, 64);
            __syncthreads();                   // Bd3 (also guards store_bufs(1-p) below)
            #pragma unroll
            for (int ct = 0; ct < 4; ++ct) {
                #pragma unroll
                for (int rgi = 0; rgi < 4; ++rgi) {
                    const int i = ibase + rgi, u = 16 * ct + m16;
                    if (u >= i + 2) acf[ct][rgi] += b2f(ring[i * 133 + 63 - i + u]);
                }
            }
        }

        #pragma unroll
        for (int rgi = 0; rgi < 4; ++rgi) {
            #pragma unroll
            for (int ct = 0; ct < 4; ++ct) {
                const float pv = exp2f(acf[ct][rgi]);
                acf[ct][rgi] = pv;
                lrun[rgi] += pv;
            }
        }
        // P -> dedicated pbuf (same-wave cross-lane exchange, no barrier)
        #pragma unroll
        for (int ct = 0; ct < 4; ++ct)
            #pragma unroll
            for (int rgi = 0; rgi < 4; ++rgi)
                pbuf[(ibase + rgi) * 68 + 16 * ct + m16] = f2bt(acf[ct][rgi]);

        short8 ap[2];
        {
            const unsigned short* pp = &pbuf[(16 * w + m16) * 68 + quad * 8];
            ap[0] = ld_frag(pp); ap[1] = ld_frag(pp + 32);
        }
        __builtin_amdgcn_s_setprio(1);
        #pragma unroll
        for (int ct = 0; ct < 4; ++ct) {
            #pragma unroll
            for (int ks = 0; ks < 2; ++ks) {
                short8 bfr = ld_frag(&vb[(16 * ct + m16) * 68 + ks * 32 + quad * 8]);
                O[ct] = MFMA16(ap[ks], bfr, O[ct]);
            }
        }
        __builtin_amdgcn_s_setprio(0);
        if (hasNext) store_bufs(1 - p);
        __syncthreads();                       // single tile-boundary barrier
    }

    #pragma unroll
    for (int rgi = 0; rgi < 4; ++rgi) {
        float l = lrun[rgi];
        #pragma unroll
        for (int off = 1; off < 16; off <<= 1)
            l += __shfl_xor(l, off);
        const float inv = 1.f / l;
        const int t = t0 + ibase + rgi;
        #pragma unroll
        for (int ct = 0; ct < 4; ++ct)
            ctx[((size_t)t * BATCH + b) * EMB + h * DHEAD + 16 * ct + m16] = f2bt(O[ct][rgi] * inv);
    }
}

// ---------------------------------------------------------------------------
// Workspace (ushort offsets), 15,990,784 ush = 31.98 MB:
//   0 inb | 2097152 posb | 3145728 w_inb | 3932160 w_posb | 4194304 free |
//   6291456 w_outb | 6553600 q_s | 8650752 k_s | 10747904 vT | 12845056 r_b |
//   13893632 ctx_b
// ---------------------------------------------------------------------------
extern "C" void kernel_launch(void* const* d_in, const int* in_sizes, int n_in,
                              void* d_out, int out_size, void* d_ws, size_t ws_size,
                              hipStream_t stream)
{
    const float* input = (const float*)d_in[0];
    const float* pos   = (const float*)d_in[1];
    const float* w_in  = (const float*)d_in[2];
    const float* w_out = (const float*)d_in[3];
    const float* w_pos = (const float*)d_in[4];
    const float* b_in  = (const float*)d_in[5];
    const float* b_out = (const float*)d_in[6];
    const float* b_pos = (const float*)d_in[7];
    const float* rwb   = (const float*)d_in[8];
    const float* rrb   = (const float*)d_in[9];

    unsigned short* ws     = (unsigned short*)d_ws;
    unsigned short* inb    = ws;
    unsigned short* posb   = ws + 2097152;
    unsigned short* w_inb  = ws + 3145728;
    unsigned short* w_posb = ws + 3932160;
    unsigned short* w_outb = ws + 6291456;
    unsigned short* q_s    = ws + 6553600;
    unsigned short* k_s    = ws + 8650752;
    unsigned short* vT     = ws + 10747904;
    unsigned short* r_b    = ws + 12845056;
    unsigned short* ctx_b  = ws + 13893632;

    cvt_all<<<4352, 256, 0, stream>>>(input, pos, w_in, w_pos, w_out,
                                      inb, posb, w_inb, w_posb, w_outb);
    gemm_qkv_pos<<<896, 256, 0, stream>>>(inb, w_inb, b_in, posb, w_posb, b_pos,
                                          q_s, k_s, vT, r_b);
    attn_mfma<<<dim3(32, 16), 256, 0, stream>>>(q_s, k_s, vT, r_b, rwb, rrb, ctx_b);
    gemm_out<<<dim3(8, 64), 256, 0, stream>>>(ctx_b, w_outb, b_out, (float*)d_out);
}